// Round 2
// baseline (477.973 us; speedup 1.0000x reference)
//
#include <hip/hip_runtime.h>
#include <hip/hip_bf16.h>
#include <stdint.h>

#define B_   16
#define CIN  512
#define HW   1600
#define E_   256
#define NTOK 80
#define CG   512
#define COUT 512
#define NHEAD 8
#define HCH  32
#define SP   (42*42)   /* padded spatial 42x42 = 1764 */

typedef __attribute__((ext_vector_type(8))) short bf16x8;
typedef __attribute__((ext_vector_type(4))) float f32x4;

__device__ __forceinline__ float bf2f(unsigned short u) {
  union { unsigned int i; float f; } v; v.i = ((unsigned int)u) << 16; return v.f;
}
__device__ __forceinline__ unsigned short f2bf(float f) {
  union { float f; unsigned int i; } v; v.f = f;
  unsigned int x = v.i;
  return (unsigned short)((x + 0x7FFFu + ((x >> 16) & 1u)) >> 16);
}

// ---- prep: x [B][CIN][HW] f32 -> xt [B][SP][CIN] bf16 (zero border pad=1) ----
__global__ void k_prep_x(const float* __restrict__ x, unsigned short* __restrict__ xt) {
  __shared__ float tile[32][33];
  int hw0 = blockIdx.x * 32, ci0 = blockIdx.y * 32, b = blockIdx.z;
  int tx = threadIdx.x, ty = threadIdx.y;
  const float* xp = x + ((size_t)b * CIN + ci0) * HW + hw0;
#pragma unroll
  for (int j = 0; j < 4; j++) tile[ty + 8 * j][tx] = xp[(size_t)(ty + 8 * j) * HW + tx];
  __syncthreads();
  int ci = ci0 + tx;
#pragma unroll
  for (int j = 0; j < 4; j++) {
    int hw = hw0 + ty + 8 * j;
    int h = hw / 40, w = hw - h * 40;
    xt[((size_t)b * SP + (size_t)(h + 1) * 42 + (w + 1)) * CIN + ci] = f2bf(tile[tx][ty + 8 * j]);
  }
}

// ---- prep: Wp [COUT][CIN][3][3] f32 -> wpb [9][COUT][CIN] bf16 ----
__global__ void k_prep_wp(const float* __restrict__ Wp, unsigned short* __restrict__ wpb) {
  int idx = blockIdx.x * 256 + threadIdx.x;   // 0..262143 = co*512+ci
  int co = idx >> 9, ci = idx & 511;
  const float* s = Wp + (size_t)idx * 9;
#pragma unroll
  for (int t = 0; t < 9; t++) wpb[((size_t)t * COUT + co) * CIN + ci] = f2bf(s[t]);
}

// ---- prep: We [E][CIN] f32 -> web bf16 ----
__global__ void k_prep_we(const float* __restrict__ We, unsigned short* __restrict__ web) {
  int idx = blockIdx.x * 256 + threadIdx.x;
  if (idx < E_ * CIN) web[idx] = f2bf(We[idx]);
}

// ---- guide_fc: gbf[b][n][e] = bf16( guide[b][n][:] . Wg[e][:] + bg[e] ) ----
__global__ void k_guide(const float* __restrict__ guide, const float* __restrict__ Wg,
                        const float* __restrict__ bg, unsigned short* __restrict__ gbf) {
  __shared__ float gr[512];
  int bn = blockIdx.x; int tid = threadIdx.x;
  const float* gp = guide + (size_t)bn * CG;
  gr[tid] = gp[tid]; gr[tid + 256] = gp[tid + 256];
  __syncthreads();
  const float4* wr4 = (const float4*)(Wg + (size_t)tid * CG);
  float acc = bg[tid];
#pragma unroll 8
  for (int c4 = 0; c4 < 128; c4++) {
    float4 wv = wr4[c4];
    const float* gg = &gr[c4 * 4];
    acc += wv.x * gg[0] + wv.y * gg[1] + wv.z * gg[2] + wv.w * gg[3];
  }
  gbf[(size_t)bn * E_ + tid] = f2bf(acc);
}

// ---- implicit-GEMM conv (bf16 MFMA, 128x128 tile, BK=32) ----
// single-barrier prefetch loop (T3-minimum) + source-side k-granule swizzle (T2, rule-21-safe)
// EPI==0: conv1x1 path -> et[b][hw][E] bf16 with BN
// EPI==1: conv3x3 path -> out[b][co][hw] f32 with BN * attn gate
template<int NTAPS, int EPI>
__launch_bounds__(256)
__global__ void k_conv(const unsigned short* __restrict__ Aw, // [NTAPS][Mtot][CIN]
                       const unsigned short* __restrict__ xt, // [B][SP][CIN]
                       const float* __restrict__ gamma, const float* __restrict__ beta,
                       const float* __restrict__ attn, float* __restrict__ outp,
                       unsigned short* __restrict__ et, int Mtot) {
  __shared__ unsigned short Al[2 * 128 * 32];
  __shared__ unsigned short Bl[2 * 128 * 32];
  int tid = threadIdx.x;
  int b = blockIdx.z;
  int m0 = blockIdx.x * 128, n0 = blockIdx.y * 128;
  int lane = tid & 63, wid = tid >> 6;
  int wr = wid >> 1, wc = wid & 1;

  // staging geometry: thread stages 16B chunk tid (rows 0..63) and tid+256 (rows 64..127)
  int mA = tid >> 2;                               // row within half-tile
  // source-side swizzle: logical k-granule for this thread's linear LDS slot
  int kq_log = (tid & 3) ^ ((tid >> 3) & 3);
  int kg = kq_log * 8;                             // element offset within BK
  int hw_a = n0 + mA;      if (hw_a > HW - 1) hw_a = HW - 1;
  int hw_b = n0 + mA + 64; if (hw_b > HW - 1) hw_b = HW - 1;
  int ha = hw_a / 40, wa = hw_a - ha * 40;
  int hb = hw_b / 40, wb = hw_b - hb * 40;
  int sp_a = ha * 42 + wa, sp_b = hb * 42 + wb;
  const unsigned short* xtb = xt + (size_t)b * SP * CIN;

  char* AlB = (char*)Al; char* BlB = (char*)Bl;
  unsigned int lds0 = (unsigned int)tid * 16u, lds1 = (unsigned int)tid * 16u + 4096u;

  const unsigned short* baseA  = Aw + ((size_t)(m0 + mA)) * CIN + kg;
  const unsigned short* baseB0 = xtb + (size_t)sp_a * CIN + kg;
  const unsigned short* baseB1 = xtb + (size_t)sp_b * CIN + kg;

  int frow = lane & 15;
  int kq16 = lane >> 4;
  int swz = (kq16 ^ ((frow >> 1) & 3)) << 4;       // matches source-side swizzle (involution)
  int aoffs[4], boffs[4];
#pragma unroll
  for (int i = 0; i < 4; i++) {
    aoffs[i] = (wr * 64 + i * 16 + frow) * 64 + swz;
    boffs[i] = (wc * 64 + i * 16 + frow) * 64 + swz;
  }

  f32x4 acc[4][4] = {};
  const int NSTEP = NTAPS * (CIN / 32);

#define STAGE(s, bufsel) do {                                                     \
    int t_ = (NTAPS == 1) ? 0 : ((s) >> 4);                                       \
    int kk_ = (NTAPS == 1) ? ((s) << 5) : (((s) & 15) << 5);                      \
    int th_ = (NTAPS == 1) ? 1 : ((t_ * 11) >> 5);                                \
    int tw_ = (NTAPS == 1) ? 1 : (t_ - th_ * 3);                                  \
    size_t aoff_ = (size_t)t_ * Mtot * CIN + kk_;                                 \
    size_t boff_ = (size_t)(th_ * 42 + tw_) * CIN + kk_;                          \
    unsigned int bo_ = (unsigned int)(bufsel) * 8192u;                            \
    __builtin_amdgcn_global_load_lds((const __attribute__((address_space(1))) unsigned int*)(baseA + aoff_),            \
        (__attribute__((address_space(3))) unsigned int*)(AlB + bo_ + lds0), 16, 0, 0);                                 \
    __builtin_amdgcn_global_load_lds((const __attribute__((address_space(1))) unsigned int*)(baseA + aoff_ + 64 * CIN), \
        (__attribute__((address_space(3))) unsigned int*)(AlB + bo_ + lds1), 16, 0, 0);                                 \
    __builtin_amdgcn_global_load_lds((const __attribute__((address_space(1))) unsigned int*)(baseB0 + boff_),           \
        (__attribute__((address_space(3))) unsigned int*)(BlB + bo_ + lds0), 16, 0, 0);                                 \
    __builtin_amdgcn_global_load_lds((const __attribute__((address_space(1))) unsigned int*)(baseB1 + boff_),           \
        (__attribute__((address_space(3))) unsigned int*)(BlB + bo_ + lds1), 16, 0, 0);                                 \
  } while (0)

  int cur = 0;
  STAGE(0, 0);
  for (int s = 0; s < NSTEP; ++s) {
    __syncthreads();                       // drains vmcnt(0): buf[cur] ready; syncs reuse of buf[cur^1]
    if (s + 1 < NSTEP) STAGE(s + 1, cur ^ 1);
    const char* Ab = AlB + cur * 8192;
    const char* Bb = BlB + cur * 8192;
    bf16x8 af[4], bfr[4];
#pragma unroll
    for (int i = 0; i < 4; i++) af[i] = *(const bf16x8*)(Ab + aoffs[i]);
#pragma unroll
    for (int i = 0; i < 4; i++) bfr[i] = *(const bf16x8*)(Bb + boffs[i]);
#pragma unroll
    for (int mi = 0; mi < 4; mi++)
#pragma unroll
      for (int ni = 0; ni < 4; ni++)
        acc[mi][ni] = __builtin_amdgcn_mfma_f32_16x16x32_bf16(af[mi], bfr[ni], acc[mi][ni], 0, 0, 0);
    cur ^= 1;
  }
#undef STAGE

  const float BN_RSQ = 0.9995003746877732f;  // 1/sqrt(1+1e-3)
  int colb = n0 + wc * 64 + frow;
  int rowb = m0 + wr * 64 + (lane >> 4) * 4;
  if (EPI == 1) {
    int head = (m0 + wr * 64) >> 6;           // 64 channels per head, uniform per wave
    const float* attn_b = attn + ((size_t)b * NHEAD + head) * HW;
    float* ob = outp + (size_t)b * COUT * HW;
#pragma unroll
    for (int mi = 0; mi < 4; mi++) {
      float sc[4], bt[4];
#pragma unroll
      for (int j = 0; j < 4; j++) {
        int co = rowb + mi * 16 + j;
        sc[j] = gamma[co] * BN_RSQ; bt[j] = beta[co];
      }
#pragma unroll
      for (int ni = 0; ni < 4; ni++) {
        int hw = colb + ni * 16;
        if (hw < HW) {
          float gate = attn_b[hw];
#pragma unroll
          for (int j = 0; j < 4; j++) {
            int co = rowb + mi * 16 + j;
            ob[(size_t)co * HW + hw] = (acc[mi][ni][j] * sc[j] + bt[j]) * gate;
          }
        }
      }
    }
  } else {
#pragma unroll
    for (int mi = 0; mi < 4; mi++) {
      float sc[4], bt[4];
#pragma unroll
      for (int j = 0; j < 4; j++) {
        int ech = rowb + mi * 16 + j;
        sc[j] = gamma[ech] * BN_RSQ; bt[j] = beta[ech];
      }
#pragma unroll
      for (int ni = 0; ni < 4; ni++) {
        int hw = colb + ni * 16;
        if (hw < HW) {
          ushort4 pk;
          pk.x = f2bf(acc[mi][ni][0] * sc[0] + bt[0]);
          pk.y = f2bf(acc[mi][ni][1] * sc[1] + bt[1]);
          pk.z = f2bf(acc[mi][ni][2] * sc[2] + bt[2]);
          pk.w = f2bf(acc[mi][ni][3] * sc[3] + bt[3]);
          *(ushort4*)(et + ((size_t)b * HW + hw) * E_ + (rowb + mi * 16)) = pk;
        }
      }
    }
  }
}

// ---- attn via MFMA: per (b,head): [HW x 32] . [32 x 80] -> max over 80, sigmoid ----
__global__ void k_attn_mfma(const unsigned short* __restrict__ et, const unsigned short* __restrict__ gbf,
                            const float* __restrict__ head_bias, float* __restrict__ attn) {
  __shared__ unsigned short gs[NTOK * HCH];   // [token][c] bf16, 5 KB
  int b = blockIdx.z, m = blockIdx.y;
  int tid = threadIdx.x, lane = tid & 63, wid = tid >> 6;
  // stage g-slice (80 tokens x 32 ch)
  for (int i = tid; i < NTOK * HCH / 8; i += 256) {
    int n = i >> 2, c = (i & 3) * 8;
    *(bf16x8*)&gs[n * HCH + c] = *(const bf16x8*)&gbf[((size_t)b * NTOK + n) * E_ + m * HCH + c];
  }
  __syncthreads();
  int col = lane & 15, kq = (lane >> 4) * 8;
  bf16x8 bfr[5];
#pragma unroll
  for (int ni = 0; ni < 5; ni++)
    bfr[ni] = *(const bf16x8*)&gs[(ni * 16 + col) * HCH + kq];

  int hw0 = blockIdx.x * 256 + wid * 64;
  bf16x8 afr[4];
#pragma unroll
  for (int mi = 0; mi < 4; mi++) {
    int hw = hw0 + mi * 16 + col; if (hw > HW - 1) hw = HW - 1;
    afr[mi] = *(const bf16x8*)&et[((size_t)b * HW + hw) * E_ + m * HCH + kq];
  }
  float hb = head_bias[m];
  float* attnp = attn + ((size_t)b * NHEAD + m) * HW;
#pragma unroll
  for (int mi = 0; mi < 4; mi++) {
    f32x4 d[5];
#pragma unroll
    for (int ni = 0; ni < 5; ni++) {
      f32x4 z = {0.f, 0.f, 0.f, 0.f};
      d[ni] = __builtin_amdgcn_mfma_f32_16x16x32_bf16(afr[mi], bfr[ni], z, 0, 0, 0);
    }
#pragma unroll
    for (int j = 0; j < 4; j++) {
      float v = fmaxf(fmaxf(fmaxf(d[0][j], d[1][j]), fmaxf(d[2][j], d[3][j])), d[4][j]);
      v = fmaxf(v, __shfl_xor(v, 1, 16));
      v = fmaxf(v, __shfl_xor(v, 2, 16));
      v = fmaxf(v, __shfl_xor(v, 4, 16));
      v = fmaxf(v, __shfl_xor(v, 8, 16));
      if (col == j) {
        int hwout = hw0 + mi * 16 + (lane >> 4) * 4 + j;
        if (hwout < HW)
          attnp[hwout] = 1.0f / (1.0f + __expf(-(v * 0.17677669529663687f + hb)));
      }
    }
  }
}

extern "C" void kernel_launch(void* const* d_in, const int* in_sizes, int n_in,
                              void* d_out, int out_size, void* d_ws, size_t ws_size,
                              hipStream_t stream) {
  const float* x         = (const float*)d_in[0];
  const float* guide     = (const float*)d_in[1];
  const float* We        = (const float*)d_in[2];
  const float* gamma_e   = (const float*)d_in[3];
  const float* beta_e    = (const float*)d_in[4];
  const float* Wg        = (const float*)d_in[5];
  const float* bg        = (const float*)d_in[6];
  const float* head_bias = (const float*)d_in[7];
  const float* Wp        = (const float*)d_in[8];
  const float* gamma_p   = (const float*)d_in[9];
  const float* beta_p    = (const float*)d_in[10];
  float* out = (float*)d_out;

  char* ws = (char*)d_ws;
  size_t off = 0;
  auto alloc = [&](size_t bytes) { char* p = ws + off; off += (bytes + 255) & ~(size_t)255; return p; };
  unsigned short* xt  = (unsigned short*)alloc((size_t)B_ * SP * CIN * 2);
  unsigned short* wpb = (unsigned short*)alloc((size_t)9 * COUT * CIN * 2);
  unsigned short* web = (unsigned short*)alloc((size_t)E_ * CIN * 2);
  unsigned short* gbf = (unsigned short*)alloc((size_t)B_ * NTOK * E_ * 2);
  unsigned short* et  = (unsigned short*)alloc((size_t)B_ * HW * E_ * 2);
  float* attn         = (float*)alloc((size_t)B_ * NHEAD * HW * 4);

  hipMemsetAsync(xt, 0, (size_t)B_ * SP * CIN * 2, stream);
  k_prep_x<<<dim3(50, 16, B_), dim3(32, 8), 0, stream>>>(x, xt);
  k_prep_wp<<<dim3(1024), dim3(256), 0, stream>>>(Wp, wpb);
  k_prep_we<<<dim3(512), dim3(256), 0, stream>>>(We, web);
  k_guide<<<dim3(B_ * NTOK), dim3(256), 0, stream>>>(guide, Wg, bg, gbf);
  k_conv<1, 0><<<dim3(2, 13, B_), dim3(256), 0, stream>>>(web, xt, gamma_e, beta_e, nullptr, nullptr, et, E_);
  k_attn_mfma<<<dim3(7, NHEAD, B_), dim3(256), 0, stream>>>(et, gbf, head_bias, attn);
  k_conv<9, 1><<<dim3(4, 13, B_), dim3(256), 0, stream>>>(wpb, xt, gamma_p, beta_p, attn, out, nullptr, COUT);
}

// Round 3
// 327.069 us; speedup vs baseline: 1.4614x; 1.4614x over previous
//
#include <hip/hip_runtime.h>
#include <hip/hip_bf16.h>
#include <stdint.h>

#define B_   16
#define CIN  512
#define HW   1600
#define E_   256
#define NTOK 80
#define CG   512
#define COUT 512
#define NHEAD 8
#define HCH  32
#define SP   (42*42)   /* padded spatial 42x42 = 1764 */

typedef __attribute__((ext_vector_type(8))) short bf16x8;
typedef __attribute__((ext_vector_type(4))) float f32x4;
typedef unsigned short ushort_t;

__device__ __forceinline__ unsigned short f2bf(float f) {
  union { float f; unsigned int i; } v; v.f = f;
  unsigned int x = v.i;
  return (unsigned short)((x + 0x7FFFu + ((x >> 16) & 1u)) >> 16);
}

// ---- prep: x [B][CIN][HW] f32 -> xt [B][SP][CIN] bf16 (zero border pad=1) ----
__global__ void k_prep_x(const float* __restrict__ x, unsigned short* __restrict__ xt) {
  __shared__ float tile[32][33];
  int hw0 = blockIdx.x * 32, ci0 = blockIdx.y * 32, b = blockIdx.z;
  int tx = threadIdx.x, ty = threadIdx.y;
  const float* xp = x + ((size_t)b * CIN + ci0) * HW + hw0;
#pragma unroll
  for (int j = 0; j < 4; j++) tile[ty + 8 * j][tx] = xp[(size_t)(ty + 8 * j) * HW + tx];
  __syncthreads();
  int ci = ci0 + tx;
#pragma unroll
  for (int j = 0; j < 4; j++) {
    int hw = hw0 + ty + 8 * j;
    int h = hw / 40, w = hw - h * 40;
    xt[((size_t)b * SP + (size_t)(h + 1) * 42 + (w + 1)) * CIN + ci] = f2bf(tile[tx][ty + 8 * j]);
  }
}

// ---- prep: Wp [COUT][CIN][3][3] f32 -> wpb2 [COUT][9*CIN] bf16 (linear-K layout) ----
__global__ void k_prep_wp(const float* __restrict__ Wp, unsigned short* __restrict__ wpb2) {
  int idx = blockIdx.x * 256 + threadIdx.x;   // 0..262143 = co*512+ci
  int co = idx >> 9, ci = idx & 511;
  const float* s = Wp + (size_t)idx * 9;
#pragma unroll
  for (int t = 0; t < 9; t++) wpb2[(size_t)co * (9 * CIN) + t * CIN + ci] = f2bf(s[t]);
}

// ---- generic f32 -> bf16 cast (vector x4) ----
__global__ void k_cast4(const float* __restrict__ in, unsigned short* __restrict__ out, int n4) {
  int i = blockIdx.x * 256 + threadIdx.x;
  if (i < n4) {
    float4 v = ((const float4*)in)[i];
    ushort4 o; o.x = f2bf(v.x); o.y = f2bf(v.y); o.z = f2bf(v.z); o.w = f2bf(v.w);
    ((ushort4*)out)[i] = o;
  }
}

// ---- implicit-GEMM conv / GEMM (bf16 MFMA, 128x128 tile, BK=32) ----
// 3-buffer LDS, prefetch distance 2, counted s_waitcnt vmcnt(4) + raw s_barrier.
// Linear-K A layout ([row][NTAPS*CIN]); B via pointer induction (+32/step, +19968 at tap-row jump).
// EPI==0: conv1x1 -> et[b][col][E] bf16 with BN      (B = xt, spatial, center tap)
// EPI==1: conv3x3 -> out[b][co][col] f32, BN * gate  (B = xt, spatial, 9 taps)
// EPI==2: GEMM    -> et[col][E] bf16, + beta bias    (B = linear rows [Ncols][CIN])
template<int NTAPS, int EPI, int MT, int NT, int NB>
__launch_bounds__(256)
__global__ void k_conv(const unsigned short* __restrict__ Aw,
                       const unsigned short* __restrict__ Bsrc,
                       const float* __restrict__ gamma, const float* __restrict__ beta,
                       const float* __restrict__ attn, float* __restrict__ outp,
                       unsigned short* __restrict__ et, int Ncols) {
  constexpr int  RS    = NTAPS * CIN;          // A row stride (elements)
  constexpr int  NSTEP = NTAPS * (CIN / 32);
  constexpr bool BLIN  = (EPI == 2);
  __shared__ unsigned short L[3 * 8192];       // 48 KB: 3 bufs x (A 8KB + B 8KB)
  char* LB = (char*)L;
  int tid = threadIdx.x;

  int wg = blockIdx.x;
  if constexpr ((MT * NT * NB) % 8 == 0 && NB > 1) {
    constexpr int q = (MT * NT * NB) / 8;      // bijective XCD swizzle (nwg%8==0)
    wg = (wg & 7) * q + (wg >> 3);
  }
  constexpr int PB = MT * NT;
  int b = wg / PB;
  int rem = wg - b * PB;
  int ntile = rem % NT;                        // ntile inner: consecutive wgs share A-tile
  int mtile = rem / NT;
  int m0 = mtile * 128, n0 = ntile * 128;

  int lane = tid & 63, wid = tid >> 6;
  int wr = wid >> 1, wc = wid & 1;

  // staging geometry: thread stages 16B chunk tid (rows 0..63) and tid+256 (rows 64..127)
  int mA = tid >> 2;
  int kq_log = (tid & 3) ^ ((tid >> 3) & 3);   // source-side k-granule swizzle (involution)
  int kg = kq_log * 8;
  unsigned int lds0 = (unsigned int)tid * 16u, lds1 = (unsigned int)tid * 16u + 4096u;

  const unsigned short* pA = Aw + (size_t)(m0 + mA) * RS + kg;
  const unsigned short* pB0;
  const unsigned short* pB1;
  if constexpr (BLIN) {
    pB0 = Bsrc + (size_t)(n0 + mA) * CIN + kg;
    pB1 = Bsrc + (size_t)(n0 + mA + 64) * CIN + kg;
  } else {
    int hw_a = n0 + mA;      if (hw_a > HW - 1) hw_a = HW - 1;
    int hw_b = n0 + mA + 64; if (hw_b > HW - 1) hw_b = HW - 1;
    int ha = hw_a / 40, wa = hw_a - ha * 40;
    int hb = hw_b / 40, wb = hw_b - hb * 40;
    int sp_a = ha * 42 + wa + ((NTAPS == 1) ? 43 : 0);   // 1x1: center tap
    int sp_b = hb * 42 + wb + ((NTAPS == 1) ? 43 : 0);
    const unsigned short* xtb = Bsrc + (size_t)b * SP * CIN;
    pB0 = xtb + (size_t)sp_a * CIN + kg;
    pB1 = xtb + (size_t)sp_b * CIN + kg;
  }

  int scnt = 0;
  auto STG = [&](unsigned bo) {
    __builtin_amdgcn_global_load_lds((const __attribute__((address_space(1))) unsigned int*)pA,
        (__attribute__((address_space(3))) unsigned int*)(LB + bo + lds0), 16, 0, 0);
    __builtin_amdgcn_global_load_lds((const __attribute__((address_space(1))) unsigned int*)(pA + 64 * RS),
        (__attribute__((address_space(3))) unsigned int*)(LB + bo + lds1), 16, 0, 0);
    __builtin_amdgcn_global_load_lds((const __attribute__((address_space(1))) unsigned int*)pB0,
        (__attribute__((address_space(3))) unsigned int*)(LB + bo + 8192u + lds0), 16, 0, 0);
    __builtin_amdgcn_global_load_lds((const __attribute__((address_space(1))) unsigned int*)pB1,
        (__attribute__((address_space(3))) unsigned int*)(LB + bo + 8192u + lds1), 16, 0, 0);
    pA += 32; pB0 += 32; pB1 += 32;
    if constexpr (NTAPS > 1) {
      ++scnt;
      if ((scnt % 48) == 0) { pB0 += 19968; pB1 += 19968; }  // tap-row jump (th+1, tw 2->0)
    }
  };

  // fragment read offsets (read-side of the involution swizzle)
  int frow = lane & 15;
  int kq16 = lane >> 4;
  int swz = (kq16 ^ ((frow >> 1) & 3)) << 4;
  int aoff[4], boff[4];
#pragma unroll
  for (int i = 0; i < 4; i++) {
    aoff[i] = (wr * 64 + i * 16 + frow) * 64 + swz;
    boff[i] = 8192 + (wc * 64 + i * 16 + frow) * 64 + swz;
  }

  f32x4 acc[4][4] = {};

  STG(0u); STG(16384u);
  unsigned r0 = 0u, r1 = 16384u, r2 = 32768u;
  for (int s = 0; s < NSTEP; ++s) {
    if (s + 1 < NSTEP) { asm volatile("s_waitcnt vmcnt(4)" ::: "memory"); }
    else               { asm volatile("s_waitcnt vmcnt(0)" ::: "memory"); }
    __builtin_amdgcn_s_barrier();           // all waves' stage-s loads have landed
    __builtin_amdgcn_sched_barrier(0);
    if (s + 2 < NSTEP) STG(r2);             // overwrites buf read two epochs ago: safe
    const char* base = LB + r0;
    bf16x8 af[4], bfv[4];
#pragma unroll
    for (int i = 0; i < 4; i++) af[i] = *(const bf16x8*)(base + aoff[i]);
#pragma unroll
    for (int i = 0; i < 4; i++) bfv[i] = *(const bf16x8*)(base + boff[i]);
#pragma unroll
    for (int mi = 0; mi < 4; mi++)
#pragma unroll
      for (int ni = 0; ni < 4; ni++)
        acc[mi][ni] = __builtin_amdgcn_mfma_f32_16x16x32_bf16(af[mi], bfv[ni], acc[mi][ni], 0, 0, 0);
    unsigned t = r0; r0 = r1; r1 = r2; r2 = t;
  }

  const float BN_RSQ = 0.9995003746877732f;  // 1/sqrt(1+1e-3)
  int colb = n0 + wc * 64 + frow;
  int rowb = m0 + wr * 64 + (lane >> 4) * 4;
  if constexpr (EPI == 1) {
    int head = (m0 + wr * 64) >> 6;           // 64 channels per head, uniform per wave
    const float* attn_b = attn + ((size_t)b * NHEAD + head) * HW;
    float* ob = outp + (size_t)b * COUT * HW;
#pragma unroll
    for (int mi = 0; mi < 4; mi++) {
      float sc[4], bt[4];
#pragma unroll
      for (int j = 0; j < 4; j++) {
        int co = rowb + mi * 16 + j;
        sc[j] = gamma[co] * BN_RSQ; bt[j] = beta[co];
      }
#pragma unroll
      for (int ni = 0; ni < 4; ni++) {
        int hw = colb + ni * 16;
        if (hw < Ncols) {
          float gate = attn_b[hw];
#pragma unroll
          for (int j = 0; j < 4; j++) {
            int co = rowb + mi * 16 + j;
            ob[(size_t)co * HW + hw] = (acc[mi][ni][j] * sc[j] + bt[j]) * gate;
          }
        }
      }
    }
  } else {
    unsigned short* etb = et + (EPI == 0 ? (size_t)b * HW * E_ : (size_t)0);
#pragma unroll
    for (int mi = 0; mi < 4; mi++) {
      float sc[4], bt[4];
#pragma unroll
      for (int j = 0; j < 4; j++) {
        int ech = rowb + mi * 16 + j;
        sc[j] = (EPI == 2) ? 1.0f : gamma[ech] * BN_RSQ;
        bt[j] = beta[ech];
      }
#pragma unroll
      for (int ni = 0; ni < 4; ni++) {
        int hw = colb + ni * 16;
        if (hw < Ncols) {
          ushort4 pk;
          pk.x = f2bf(acc[mi][ni][0] * sc[0] + bt[0]);
          pk.y = f2bf(acc[mi][ni][1] * sc[1] + bt[1]);
          pk.z = f2bf(acc[mi][ni][2] * sc[2] + bt[2]);
          pk.w = f2bf(acc[mi][ni][3] * sc[3] + bt[3]);
          *(ushort4*)(etb + (size_t)hw * E_ + (rowb + mi * 16)) = pk;
        }
      }
    }
  }
}

// ---- attn via MFMA: per (b,head): [HW x 32] . [32 x 80] -> max over 80, sigmoid ----
__global__ void k_attn_mfma(const unsigned short* __restrict__ et, const unsigned short* __restrict__ gbf,
                            const float* __restrict__ head_bias, float* __restrict__ attn) {
  __shared__ unsigned short gs[NTOK * HCH];   // [token][c] bf16, 5 KB
  int b = blockIdx.z, m = blockIdx.y;
  int tid = threadIdx.x, lane = tid & 63, wid = tid >> 6;
  for (int i = tid; i < NTOK * HCH / 8; i += 256) {
    int n = i >> 2, c = (i & 3) * 8;
    *(bf16x8*)&gs[n * HCH + c] = *(const bf16x8*)&gbf[((size_t)b * NTOK + n) * E_ + m * HCH + c];
  }
  __syncthreads();
  int col = lane & 15, kq = (lane >> 4) * 8;
  bf16x8 bfr[5];
#pragma unroll
  for (int ni = 0; ni < 5; ni++)
    bfr[ni] = *(const bf16x8*)&gs[(ni * 16 + col) * HCH + kq];

  int hw0 = blockIdx.x * 256 + wid * 64;
  bf16x8 afr[4];
#pragma unroll
  for (int mi = 0; mi < 4; mi++) {
    int hw = hw0 + mi * 16 + col; if (hw > HW - 1) hw = HW - 1;
    afr[mi] = *(const bf16x8*)&et[((size_t)b * HW + hw) * E_ + m * HCH + kq];
  }
  float hb = head_bias[m];
  float* attnp = attn + ((size_t)b * NHEAD + m) * HW;
#pragma unroll
  for (int mi = 0; mi < 4; mi++) {
    f32x4 d[5];
#pragma unroll
    for (int ni = 0; ni < 5; ni++) {
      f32x4 z = {0.f, 0.f, 0.f, 0.f};
      d[ni] = __builtin_amdgcn_mfma_f32_16x16x32_bf16(afr[mi], bfr[ni], z, 0, 0, 0);
    }
#pragma unroll
    for (int j = 0; j < 4; j++) {
      float v = fmaxf(fmaxf(fmaxf(d[0][j], d[1][j]), fmaxf(d[2][j], d[3][j])), d[4][j]);
      v = fmaxf(v, __shfl_xor(v, 1, 16));
      v = fmaxf(v, __shfl_xor(v, 2, 16));
      v = fmaxf(v, __shfl_xor(v, 4, 16));
      v = fmaxf(v, __shfl_xor(v, 8, 16));
      if (col == j) {
        int hwout = hw0 + mi * 16 + (lane >> 4) * 4 + j;
        if (hwout < HW)
          attnp[hwout] = 1.0f / (1.0f + __expf(-(v * 0.17677669529663687f + hb)));
      }
    }
  }
}

extern "C" void kernel_launch(void* const* d_in, const int* in_sizes, int n_in,
                              void* d_out, int out_size, void* d_ws, size_t ws_size,
                              hipStream_t stream) {
  const float* x         = (const float*)d_in[0];
  const float* guide     = (const float*)d_in[1];
  const float* We        = (const float*)d_in[2];
  const float* gamma_e   = (const float*)d_in[3];
  const float* beta_e    = (const float*)d_in[4];
  const float* Wg        = (const float*)d_in[5];
  const float* bg        = (const float*)d_in[6];
  const float* head_bias = (const float*)d_in[7];
  const float* Wp        = (const float*)d_in[8];
  const float* gamma_p   = (const float*)d_in[9];
  const float* beta_p    = (const float*)d_in[10];
  float* out = (float*)d_out;

  char* ws = (char*)d_ws;
  size_t off = 0;
  auto alloc = [&](size_t bytes) { char* p = ws + off; off += (bytes + 255) & ~(size_t)255; return p; };
  unsigned short* xt   = (unsigned short*)alloc((size_t)B_ * SP * CIN * 2);
  unsigned short* wpb2 = (unsigned short*)alloc((size_t)COUT * 9 * CIN * 2);
  unsigned short* web  = (unsigned short*)alloc((size_t)E_ * CIN * 2);
  unsigned short* wgb  = (unsigned short*)alloc((size_t)E_ * CG * 2);
  unsigned short* gub  = (unsigned short*)alloc((size_t)B_ * NTOK * CG * 2);
  unsigned short* gbf  = (unsigned short*)alloc((size_t)B_ * NTOK * E_ * 2);
  unsigned short* et   = (unsigned short*)alloc((size_t)B_ * HW * E_ * 2);
  float* attn          = (float*)alloc((size_t)B_ * NHEAD * HW * 4);

  hipMemsetAsync(xt, 0, (size_t)B_ * SP * CIN * 2, stream);
  k_prep_x<<<dim3(50, 16, B_), dim3(32, 8), 0, stream>>>(x, xt);
  k_prep_wp<<<dim3(1024), dim3(256), 0, stream>>>(Wp, wpb2);
  k_cast4<<<dim3(128), dim3(256), 0, stream>>>(We, web, E_ * CIN / 4);
  k_cast4<<<dim3(128), dim3(256), 0, stream>>>(Wg, wgb, E_ * CG / 4);
  k_cast4<<<dim3(640), dim3(256), 0, stream>>>(guide, gub, B_ * NTOK * CG / 4);
  // guide_fc as GEMM: C[256 x 1280] = Wg . guide^T, +bg, -> gbf[token][e] bf16
  k_conv<1, 2, 2, 10, 1><<<dim3(20), dim3(256), 0, stream>>>(wgb, gub, bg, bg, nullptr, nullptr, gbf, B_ * NTOK);
  // embed conv1x1 + BN -> et[b][hw][E]
  k_conv<1, 0, 2, 13, B_><<<dim3(2 * 13 * B_), dim3(256), 0, stream>>>(web, xt, gamma_e, beta_e, nullptr, nullptr, et, HW);
  k_attn_mfma<<<dim3(7, NHEAD, B_), dim3(256), 0, stream>>>(et, gbf, head_bias, attn);
  // project conv3x3 + BN, gated
  k_conv<9, 1, 4, 13, B_><<<dim3(4 * 13 * B_), dim3(256), 0, stream>>>(wpb2, xt, gamma_p, beta_p, attn, out, nullptr, HW);
}

// Round 4
// 309.464 us; speedup vs baseline: 1.5445x; 1.0569x over previous
//
#include <hip/hip_runtime.h>
#include <hip/hip_bf16.h>
#include <stdint.h>

#define B_   16
#define CIN  512
#define HW   1600
#define E_   256
#define NTOK 80
#define CG   512
#define COUT 512
#define NHEAD 8
#define HCH  32
#define SP   (42*42)   /* padded spatial 42x42 = 1764 */

typedef __attribute__((ext_vector_type(8))) short bf16x8;
typedef __attribute__((ext_vector_type(4))) float f32x4;

__device__ __forceinline__ unsigned short f2bf(float f) {
  union { float f; unsigned int i; } v; v.f = f;
  unsigned int x = v.i;
  return (unsigned short)((x + 0x7FFFu + ((x >> 16) & 1u)) >> 16);
}

// ---- prep: x [B][CIN][HW] f32 -> xt [B][SP][CIN] bf16 (zero border pad=1) ----
__global__ void k_prep_x(const float* __restrict__ x, unsigned short* __restrict__ xt) {
  __shared__ float tile[32][33];
  int hw0 = blockIdx.x * 32, ci0 = blockIdx.y * 32, b = blockIdx.z;
  int tx = threadIdx.x, ty = threadIdx.y;
  const float* xp = x + ((size_t)b * CIN + ci0) * HW + hw0;
#pragma unroll
  for (int j = 0; j < 4; j++) tile[ty + 8 * j][tx] = xp[(size_t)(ty + 8 * j) * HW + tx];
  __syncthreads();
  int ci = ci0 + tx;
#pragma unroll
  for (int j = 0; j < 4; j++) {
    int hw = hw0 + ty + 8 * j;
    int h = hw / 40, w = hw - h * 40;
    xt[((size_t)b * SP + (size_t)(h + 1) * 42 + (w + 1)) * CIN + ci] = f2bf(tile[tx][ty + 8 * j]);
  }
}

// ---- prep: Wp [COUT][CIN][3][3] f32 -> wpb2 [COUT][9*CIN] bf16 (linear-K layout) ----
__global__ void k_prep_wp(const float* __restrict__ Wp, unsigned short* __restrict__ wpb2) {
  int idx = blockIdx.x * 256 + threadIdx.x;   // 0..262143 = co*512+ci
  int co = idx >> 9, ci = idx & 511;
  const float* s = Wp + (size_t)idx * 9;
#pragma unroll
  for (int t = 0; t < 9; t++) wpb2[(size_t)co * (9 * CIN) + t * CIN + ci] = f2bf(s[t]);
}

// ---- fused f32 -> bf16 casts: We (32768 x4), Wg (32768 x4), guide (163840 x4) ----
__global__ void k_cast_all(const float* __restrict__ We, unsigned short* __restrict__ web,
                           const float* __restrict__ Wg, unsigned short* __restrict__ wgb,
                           const float* __restrict__ gu, unsigned short* __restrict__ gub) {
  int i = blockIdx.x * 256 + threadIdx.x;
  const float* src; unsigned short* dst; int j;
  if (i < 32768)       { src = We; dst = web; j = i; }
  else if (i < 65536)  { src = Wg; dst = wgb; j = i - 32768; }
  else                 { src = gu; dst = gub; j = i - 65536; }
  float4 v = ((const float4*)src)[j];
  ushort4 o; o.x = f2bf(v.x); o.y = f2bf(v.y); o.z = f2bf(v.z); o.w = f2bf(v.w);
  ((ushort4*)dst)[j] = o;
}

// ---- implicit-GEMM conv / GEMM (bf16 MFMA, 256x128 tile, BK=32, wave-tile 128x64) ----
// 3-buffer LDS, prefetch distance 2, counted s_waitcnt vmcnt(6) + raw s_barrier.
// N flattened across batch (col = b*1600 + hw). Linear-K A layout; B pointer induction.
// EPI==0: conv1x1 -> et[b][hw][E] bf16 with BN      (B = xt, spatial, center tap)
// EPI==1: conv3x3 -> out[b][co][hw] f32, BN * gate  (B = xt, spatial, 9 taps)
// EPI==2: GEMM    -> et[col][E] bf16, + beta bias   (B = linear rows [cols][CIN])
template<int NTAPS, int EPI, int MT, int NT, int SWZ>
__launch_bounds__(256, 2)
__global__ void k_conv(const unsigned short* __restrict__ Aw,
                       const unsigned short* __restrict__ Bsrc,
                       const float* __restrict__ gamma, const float* __restrict__ beta,
                       const float* __restrict__ attn, float* __restrict__ outp,
                       unsigned short* __restrict__ et) {
  constexpr int  RS    = NTAPS * CIN;          // A row stride (elements)
  constexpr int  NSTEP = NTAPS * (CIN / 32);
  constexpr bool BLIN  = (EPI == 2);
  __shared__ unsigned short L[3 * 12288];      // 72 KB: 3 bufs x (A 16KB + B 8KB)
  char* LB = (char*)L;
  int tid = threadIdx.x;

  int wg = blockIdx.x;
  if constexpr (SWZ) {
    constexpr int q = MT * NT / 8;             // bijective XCD swizzle (grid%8==0)
    wg = (wg & 7) * q + (wg >> 3);
  }
  int mtile = wg / NT, ntile = wg % NT;        // ntile inner: consecutive wgs share A
  int m0 = mtile * 256, n0 = ntile * 128;

  int lane = tid & 63, wid = tid >> 6;
  int wr = wid >> 1, wc = wid & 1;

  // staging: thread stages A rows rA+{0,64,128,192}, B cols rA+{0,64}; 16B granules
  int rA = tid >> 2;
  int kq = ((tid & 3) ^ ((tid >> 3) & 3)) * 8; // source-side k-granule swizzle (involution)
  const unsigned short* pA = Aw + (size_t)(m0 + rA) * RS + kq;
  const unsigned short* pB0;
  const unsigned short* pB1;
  if constexpr (BLIN) {
    pB0 = Bsrc + (size_t)(n0 + rA) * CIN + kq;
    pB1 = pB0 + (size_t)64 * CIN;
  } else {
    int c0 = n0 + rA, c1 = c0 + 64;
    int b0 = c0 / 1600, hw0 = c0 - b0 * 1600;
    int b1 = c1 / 1600, hw1 = c1 - b1 * 1600;
    int h0 = hw0 / 40, w0 = hw0 - h0 * 40;
    int h1 = hw1 / 40, w1 = hw1 - h1 * 40;
    constexpr int ctr = (NTAPS == 1) ? 43 : 0; // 1x1: center tap
    pB0 = Bsrc + ((size_t)b0 * SP + h0 * 42 + w0 + ctr) * CIN + kq;
    pB1 = Bsrc + ((size_t)b1 * SP + h1 * 42 + w1 + ctr) * CIN + kq;
  }

  int scnt = 0;
  auto STG = [&](unsigned bo) {
#define GL(src, dst) __builtin_amdgcn_global_load_lds((const __attribute__((address_space(1))) unsigned int*)(src), \
        (__attribute__((address_space(3))) unsigned int*)(dst), 16, 0, 0)
    GL(pA,            LB + bo +      0u + tid * 16u);
    GL(pA +  64 * RS, LB + bo +  4096u + tid * 16u);
    GL(pA + 128 * RS, LB + bo +  8192u + tid * 16u);
    GL(pA + 192 * RS, LB + bo + 12288u + tid * 16u);
    GL(pB0,           LB + bo + 16384u + tid * 16u);
    GL(pB1,           LB + bo + 20480u + tid * 16u);
#undef GL
    pA += 32; pB0 += 32; pB1 += 32;
    if constexpr (NTAPS > 1) {
      ++scnt;
      if ((scnt % 48) == 0) { pB0 += 19968; pB1 += 19968; }  // tap-row jump
    }
  };

  // fragment read offsets (read-side of the involution swizzle)
  int frow = lane & 15;
  int swz = ((lane >> 4) ^ ((frow >> 1) & 3)) << 4;
  int aoff[8], boff[4];
#pragma unroll
  for (int i = 0; i < 8; i++) aoff[i] = (wr * 128 + i * 16 + frow) * 64 + swz;
#pragma unroll
  for (int i = 0; i < 4; i++) boff[i] = 16384 + (wc * 64 + i * 16 + frow) * 64 + swz;

  f32x4 acc[8][4] = {};

  STG(0u); STG(24576u);
  unsigned r0 = 0u, r1 = 24576u, r2 = 49152u;
  for (int s = 0; s < NSTEP; ++s) {
    if (s + 1 < NSTEP) { asm volatile("s_waitcnt vmcnt(6)" ::: "memory"); }
    else               { asm volatile("s_waitcnt vmcnt(0)" ::: "memory"); }
    __builtin_amdgcn_s_barrier();           // all waves' stage-s loads have landed
    __builtin_amdgcn_sched_barrier(0);
    if (s + 2 < NSTEP) STG(r2);             // overwrites buf read two epochs ago: safe
    const char* base = LB + r0;
    bf16x8 af[8], bv[4];
#pragma unroll
    for (int i = 0; i < 8; i++) af[i] = *(const bf16x8*)(base + aoff[i]);
#pragma unroll
    for (int i = 0; i < 4; i++) bv[i] = *(const bf16x8*)(base + boff[i]);
#pragma unroll
    for (int mi = 0; mi < 8; mi++)
#pragma unroll
      for (int ni = 0; ni < 4; ni++)
        acc[mi][ni] = __builtin_amdgcn_mfma_f32_16x16x32_bf16(af[mi], bv[ni], acc[mi][ni], 0, 0, 0);
    unsigned t = r0; r0 = r1; r1 = r2; r2 = t;
  }

  const float BN_RSQ = 0.9995003746877732f;  // 1/sqrt(1+1e-3)
  int colb = n0 + wc * 64 + frow;
  int rowb = m0 + wr * 128 + (lane >> 4) * 4;
  if constexpr (EPI == 1) {
    float* ob = outp;
#pragma unroll
    for (int mi = 0; mi < 8; mi++) {
      int head = (m0 + wr * 128 + mi * 16) >> 6;   // uniform per (wave,mi)
      float sc[4], bt[4];
#pragma unroll
      for (int j = 0; j < 4; j++) {
        int co = rowb + mi * 16 + j;
        sc[j] = gamma[co] * BN_RSQ; bt[j] = beta[co];
      }
#pragma unroll
      for (int ni = 0; ni < 4; ni++) {
        int col = colb + ni * 16;
        int b = col / 1600, hw = col - b * 1600;
        float gate = attn[((size_t)b * NHEAD + head) * HW + hw];
#pragma unroll
        for (int j = 0; j < 4; j++) {
          int co = rowb + mi * 16 + j;
          ob[((size_t)b * COUT + co) * HW + hw] = (acc[mi][ni][j] * sc[j] + bt[j]) * gate;
        }
      }
    }
  } else {
#pragma unroll
    for (int mi = 0; mi < 8; mi++) {
      float sc[4], bt[4];
#pragma unroll
      for (int j = 0; j < 4; j++) {
        int ech = rowb + mi * 16 + j;
        sc[j] = (EPI == 2) ? 1.0f : gamma[ech] * BN_RSQ;
        bt[j] = beta[ech];
      }
#pragma unroll
      for (int ni = 0; ni < 4; ni++) {
        int col = colb + ni * 16;
        size_t rowbase;
        if constexpr (EPI == 2) {
          rowbase = (size_t)col * E_;
        } else {
          int b = col / 1600, hw = col - b * 1600;
          rowbase = ((size_t)b * HW + hw) * E_;
        }
        ushort4 pk;
        pk.x = f2bf(acc[mi][ni][0] * sc[0] + bt[0]);
        pk.y = f2bf(acc[mi][ni][1] * sc[1] + bt[1]);
        pk.z = f2bf(acc[mi][ni][2] * sc[2] + bt[2]);
        pk.w = f2bf(acc[mi][ni][3] * sc[3] + bt[3]);
        *(ushort4*)(et + rowbase + (rowb + mi * 16)) = pk;
      }
    }
  }
}

// ---- attn via MFMA: per (b,head): [HW x 32] . [32 x 80] -> max over 80, sigmoid ----
__global__ void k_attn_mfma(const unsigned short* __restrict__ et, const unsigned short* __restrict__ gbf,
                            const float* __restrict__ head_bias, float* __restrict__ attn) {
  __shared__ unsigned short gs[NTOK * HCH];   // [token][c] bf16, 5 KB
  int b = blockIdx.z, m = blockIdx.y;
  int tid = threadIdx.x, lane = tid & 63, wid = tid >> 6;
  for (int i = tid; i < NTOK * HCH / 8; i += 256) {
    int n = i >> 2, c = (i & 3) * 8;
    *(bf16x8*)&gs[n * HCH + c] = *(const bf16x8*)&gbf[((size_t)b * NTOK + n) * E_ + m * HCH + c];
  }
  __syncthreads();
  int col = lane & 15, kq = (lane >> 4) * 8;
  bf16x8 bfr[5];
#pragma unroll
  for (int ni = 0; ni < 5; ni++)
    bfr[ni] = *(const bf16x8*)&gs[(ni * 16 + col) * HCH + kq];

  int hw0 = blockIdx.x * 256 + wid * 64;
  bf16x8 afr[4];
#pragma unroll
  for (int mi = 0; mi < 4; mi++) {
    int hw = hw0 + mi * 16 + col; if (hw > HW - 1) hw = HW - 1;
    afr[mi] = *(const bf16x8*)&et[((size_t)b * HW + hw) * E_ + m * HCH + kq];
  }
  float hb = head_bias[m];
  float* attnp = attn + ((size_t)b * NHEAD + m) * HW;
#pragma unroll
  for (int mi = 0; mi < 4; mi++) {
    f32x4 d[5];
#pragma unroll
    for (int ni = 0; ni < 5; ni++) {
      f32x4 z = {0.f, 0.f, 0.f, 0.f};
      d[ni] = __builtin_amdgcn_mfma_f32_16x16x32_bf16(afr[mi], bfr[ni], z, 0, 0, 0);
    }
#pragma unroll
    for (int j = 0; j < 4; j++) {
      float v = fmaxf(fmaxf(fmaxf(d[0][j], d[1][j]), fmaxf(d[2][j], d[3][j])), d[4][j]);
      v = fmaxf(v, __shfl_xor(v, 1, 16));
      v = fmaxf(v, __shfl_xor(v, 2, 16));
      v = fmaxf(v, __shfl_xor(v, 4, 16));
      v = fmaxf(v, __shfl_xor(v, 8, 16));
      if (col == j) {
        int hwout = hw0 + mi * 16 + (lane >> 4) * 4 + j;
        if (hwout < HW)
          attnp[hwout] = 1.0f / (1.0f + __expf(-(v * 0.17677669529663687f + hb)));
      }
    }
  }
}

extern "C" void kernel_launch(void* const* d_in, const int* in_sizes, int n_in,
                              void* d_out, int out_size, void* d_ws, size_t ws_size,
                              hipStream_t stream) {
  const float* x         = (const float*)d_in[0];
  const float* guide     = (const float*)d_in[1];
  const float* We        = (const float*)d_in[2];
  const float* gamma_e   = (const float*)d_in[3];
  const float* beta_e    = (const float*)d_in[4];
  const float* Wg        = (const float*)d_in[5];
  const float* bg        = (const float*)d_in[6];
  const float* head_bias = (const float*)d_in[7];
  const float* Wp        = (const float*)d_in[8];
  const float* gamma_p   = (const float*)d_in[9];
  const float* beta_p    = (const float*)d_in[10];
  float* out = (float*)d_out;

  char* ws = (char*)d_ws;
  size_t off = 0;
  auto alloc = [&](size_t bytes) { char* p = ws + off; off += (bytes + 255) & ~(size_t)255; return p; };
  unsigned short* xt   = (unsigned short*)alloc((size_t)B_ * SP * CIN * 2);
  unsigned short* wpb2 = (unsigned short*)alloc((size_t)COUT * 9 * CIN * 2);
  unsigned short* web  = (unsigned short*)alloc((size_t)E_ * CIN * 2);
  unsigned short* wgb  = (unsigned short*)alloc((size_t)E_ * CG * 2);
  unsigned short* gub  = (unsigned short*)alloc((size_t)B_ * NTOK * CG * 2);
  unsigned short* gbf  = (unsigned short*)alloc((size_t)B_ * NTOK * E_ * 2);
  unsigned short* et   = (unsigned short*)alloc((size_t)B_ * HW * E_ * 2);
  float* attn          = (float*)alloc((size_t)B_ * NHEAD * HW * 4);

  hipMemsetAsync(xt, 0, (size_t)B_ * SP * CIN * 2, stream);
  k_prep_x<<<dim3(50, 16, B_), dim3(32, 8), 0, stream>>>(x, xt);
  k_prep_wp<<<dim3(1024), dim3(256), 0, stream>>>(Wp, wpb2);
  k_cast_all<<<dim3(896), dim3(256), 0, stream>>>(We, web, Wg, wgb, guide, gub);
  // guide_fc as GEMM: C[256 x 1280] = Wg . guide^T, +bg -> gbf[token][e] bf16
  k_conv<1, 2, 1, 10, 0><<<dim3(10), dim3(256), 0, stream>>>(wgb, gub, bg, bg, nullptr, nullptr, gbf);
  // embed conv1x1 + BN -> et[b][hw][E]
  k_conv<1, 0, 1, 200, 1><<<dim3(200), dim3(256), 0, stream>>>(web, xt, gamma_e, beta_e, nullptr, nullptr, et);
  k_attn_mfma<<<dim3(7, NHEAD, B_), dim3(256), 0, stream>>>(et, gbf, head_bias, attn);
  // project conv3x3 + BN, gated
  k_conv<9, 1, 2, 200, 1><<<dim3(400), dim3(256), 0, stream>>>(wpb2, xt, gamma_p, beta_p, attn, out, nullptr);
}

// Round 5
// 302.104 us; speedup vs baseline: 1.5821x; 1.0244x over previous
//
#include <hip/hip_runtime.h>
#include <hip/hip_bf16.h>
#include <stdint.h>

#define B_   16
#define CIN  512
#define HW   1600
#define E_   256
#define NTOK 80
#define CG   512
#define COUT 512
#define NHEAD 8
#define HCH  32
#define SP   (42*42)   /* padded spatial 42x42 = 1764 */

typedef __attribute__((ext_vector_type(8))) short bf16x8;
typedef __attribute__((ext_vector_type(4))) float f32x4;

__device__ __forceinline__ unsigned short f2bf(float f) {
  union { float f; unsigned int i; } v; v.f = f;
  unsigned int x = v.i;
  return (unsigned short)((x + 0x7FFFu + ((x >> 16) & 1u)) >> 16);
}

// ---- prep: x [B][CIN][HW] f32 -> xt [B][SP][CIN] bf16 (zero border pad=1) ----
__global__ void k_prep_x(const float* __restrict__ x, unsigned short* __restrict__ xt) {
  __shared__ float tile[32][33];
  int hw0 = blockIdx.x * 32, ci0 = blockIdx.y * 32, b = blockIdx.z;
  int tx = threadIdx.x, ty = threadIdx.y;
  const float* xp = x + ((size_t)b * CIN + ci0) * HW + hw0;
#pragma unroll
  for (int j = 0; j < 4; j++) tile[ty + 8 * j][tx] = xp[(size_t)(ty + 8 * j) * HW + tx];
  __syncthreads();
  int ci = ci0 + tx;
#pragma unroll
  for (int j = 0; j < 4; j++) {
    int hw = hw0 + ty + 8 * j;
    int h = hw / 40, w = hw - h * 40;
    xt[((size_t)b * SP + (size_t)(h + 1) * 42 + (w + 1)) * CIN + ci] = f2bf(tile[tx][ty + 8 * j]);
  }
}

// ---- prep: Wp [COUT][CIN][3][3] f32 -> wpb2 [COUT][9*CIN] bf16 (linear-K layout) ----
__global__ void k_prep_wp(const float* __restrict__ Wp, unsigned short* __restrict__ wpb2) {
  int idx = blockIdx.x * 256 + threadIdx.x;   // 0..262143 = co*512+ci
  int co = idx >> 9, ci = idx & 511;
  const float* s = Wp + (size_t)idx * 9;
#pragma unroll
  for (int t = 0; t < 9; t++) wpb2[(size_t)co * (9 * CIN) + t * CIN + ci] = f2bf(s[t]);
}

// ---- fused f32 -> bf16 casts: We (32768 x4), Wg (32768 x4), guide (163840 x4) ----
__global__ void k_cast_all(const float* __restrict__ We, unsigned short* __restrict__ web,
                           const float* __restrict__ Wg, unsigned short* __restrict__ wgb,
                           const float* __restrict__ gu, unsigned short* __restrict__ gub) {
  int i = blockIdx.x * 256 + threadIdx.x;
  const float* src; unsigned short* dst; int j;
  if (i < 32768)       { src = We; dst = web; j = i; }
  else if (i < 65536)  { src = Wg; dst = wgb; j = i - 32768; }
  else                 { src = gu; dst = gub; j = i - 65536; }
  float4 v = ((const float4*)src)[j];
  ushort4 o; o.x = f2bf(v.x); o.y = f2bf(v.y); o.z = f2bf(v.z); o.w = f2bf(v.w);
  ((ushort4*)dst)[j] = o;
}

// ---- fused GEMM kernel: 305 wgs x 512 threads, 256x256 tile, BK=32 ----
// wg 0..199  : conv3x3  C[512][25600], K=4608 -> out f32 (BN, UNGATED)
// wg 200..299: conv1x1  C[256][25600], K=512  -> et bf16 (BN)
// wg 300..304: guide fc C[256][1280],  K=512  -> gbf bf16 (+bg)
// 8 waves 2Mx4N (wave-tile 128x64); 3-buf LDS dist-2 prefetch, counted vmcnt(4);
// each K-step = 2 phases {ds_read || stage ; barrier ; setprio ; 16 MFMA ; setprio ; barrier}.
__global__ __launch_bounds__(512, 2)
void k_fused(const unsigned short* __restrict__ wpb2, const unsigned short* __restrict__ web,
             const unsigned short* __restrict__ wgb,  const unsigned short* __restrict__ xt,
             const unsigned short* __restrict__ gub,
             const float* __restrict__ gamma_e, const float* __restrict__ beta_e,
             const float* __restrict__ gamma_p, const float* __restrict__ beta_p,
             const float* __restrict__ bg,
             float* __restrict__ out, unsigned short* __restrict__ et,
             unsigned short* __restrict__ gbf) {
  __shared__ unsigned short L[3 * 16384];      // 96 KB: 3 bufs x (A 16KB + B 16KB)
  char* LB = (char*)L;
  int tid = threadIdx.x;
  int wg = blockIdx.x;

  int role, m0, n0;
  if (wg < 200)      { int w = (wg & 7) * 25 + (wg >> 3);      // bijective XCD swizzle
                       role = 0; m0 = (w / 100) * 256; n0 = (w % 100) * 256; }
  else if (wg < 300) { role = 1; m0 = 0; n0 = (wg - 200) * 256; }
  else               { role = 2; m0 = 0; n0 = (wg - 300) * 256; }

  const int RS    = (role == 0) ? 9 * CIN : CIN;
  const int NSTEP = (role == 0) ? 144 : 16;
  const bool tapjump = (role == 0);
  const unsigned short* Aw = (role == 0) ? wpb2 : (role == 1) ? web : wgb;

  int lane = tid & 63, wid = tid >> 6;
  int wr = wid >> 2, wc = wid & 3;

  // staging: 512 threads; A unit = 128 rows x 4 granules (16B); 2 A-units, 2 B-units per step
  int rloc = tid >> 2;
  int kq_g = ((tid & 3) ^ ((tid >> 3) & 3)) * 8;   // source-side involution swizzle
  const unsigned short* pA = Aw + (size_t)(m0 + rloc) * RS + kq_g;
  const unsigned short* pB0;
  const unsigned short* pB1;
  if (role == 2) {
    pB0 = gub + (size_t)(n0 + rloc) * CIN + kq_g;
    pB1 = pB0 + (size_t)128 * CIN;
  } else {
    int c0 = n0 + rloc, c1 = c0 + 128;
    int b0 = c0 / 1600, hw0 = c0 - b0 * 1600;
    int b1 = c1 / 1600, hw1 = c1 - b1 * 1600;
    int h0 = hw0 / 40, w0 = hw0 - h0 * 40;
    int h1 = hw1 / 40, w1 = hw1 - h1 * 40;
    int ctr = (role == 1) ? 43 : 0;              // 1x1 uses center tap of padded frame
    pB0 = xt + ((size_t)b0 * SP + h0 * 42 + w0 + ctr) * CIN + kq_g;
    pB1 = xt + ((size_t)b1 * SP + h1 * 42 + w1 + ctr) * CIN + kq_g;
  }

  int scnt = 0;
#define GL(src, dst) __builtin_amdgcn_global_load_lds((const __attribute__((address_space(1))) unsigned int*)(src), \
        (__attribute__((address_space(3))) unsigned int*)(dst), 16, 0, 0)
  auto STG_A = [&](unsigned bo) {
    GL(pA,            LB + bo +     0u + tid * 16u);
    GL(pA + 128 * RS, LB + bo +  8192u + tid * 16u);
  };
  auto STG_B = [&](unsigned bo) {
    GL(pB0,           LB + bo + 16384u + tid * 16u);
    GL(pB1,           LB + bo + 24576u + tid * 16u);
  };
  auto ADV = [&]() {
    pA += 32; pB0 += 32; pB1 += 32;
    if (tapjump) { ++scnt; if ((scnt % 48) == 0) { pB0 += 19968; pB1 += 19968; } }
  };

  // fragment read offsets (read-side of involution swizzle)
  int frow = lane & 15;
  int sg = ((lane >> 4) ^ ((frow >> 1) & 3)) << 4;
  int aoff[8], boff[4];
#pragma unroll
  for (int i = 0; i < 8; i++) aoff[i] = (wr * 128 + i * 16 + frow) * 64 + sg;
#pragma unroll
  for (int i = 0; i < 4; i++) boff[i] = 16384 + (wc * 64 + i * 16 + frow) * 64 + sg;

  f32x4 acc[8][4] = {};

  STG_A(0u); STG_B(0u); ADV();
  STG_A(32768u); STG_B(32768u); ADV();
  unsigned r0 = 0u, r1 = 32768u, r2 = 65536u;

  for (int s = 0; s < NSTEP; ++s) {
    if (s + 1 < NSTEP) { asm volatile("s_waitcnt vmcnt(4)" ::: "memory"); }
    else               { asm volatile("s_waitcnt vmcnt(0)" ::: "memory"); }
    __builtin_amdgcn_s_barrier();            // buf[s] staged for all waves; r2 free
    __builtin_amdgcn_sched_barrier(0);
    const char* base = LB + r0;
    bool pre = (s + 2 < NSTEP);
    bf16x8 af[8], bv[4];
    // phase A: m-half 0
#pragma unroll
    for (int i = 0; i < 4; i++) af[i] = *(const bf16x8*)(base + aoff[i]);
#pragma unroll
    for (int i = 0; i < 4; i++) bv[i] = *(const bf16x8*)(base + boff[i]);
    if (pre) STG_A(r2);
    __builtin_amdgcn_s_barrier();
    __builtin_amdgcn_s_setprio(1);
#pragma unroll
    for (int mi = 0; mi < 4; mi++)
#pragma unroll
      for (int ni = 0; ni < 4; ni++)
        acc[mi][ni] = __builtin_amdgcn_mfma_f32_16x16x32_bf16(af[mi], bv[ni], acc[mi][ni], 0, 0, 0);
    __builtin_amdgcn_s_setprio(0);
    __builtin_amdgcn_s_barrier();
    // phase B: m-half 1
#pragma unroll
    for (int i = 4; i < 8; i++) af[i] = *(const bf16x8*)(base + aoff[i]);
    if (pre) { STG_B(r2); ADV(); }
    __builtin_amdgcn_s_barrier();
    __builtin_amdgcn_s_setprio(1);
#pragma unroll
    for (int mi = 4; mi < 8; mi++)
#pragma unroll
      for (int ni = 0; ni < 4; ni++)
        acc[mi][ni] = __builtin_amdgcn_mfma_f32_16x16x32_bf16(af[mi], bv[ni], acc[mi][ni], 0, 0, 0);
    __builtin_amdgcn_s_setprio(0);
    unsigned t = r0; r0 = r1; r1 = r2; r2 = t;
  }
#undef GL

  const float BN_RSQ = 0.9995003746877732f;  // 1/sqrt(1+1e-3)
  int colb = n0 + wc * 64 + frow;
  int rowb = m0 + wr * 128 + (lane >> 4) * 4;
  if (role == 0) {                           // conv3x3: f32 ungated out[b][co][hw]
#pragma unroll
    for (int mi = 0; mi < 8; mi++) {
      float sc[4], bt[4];
#pragma unroll
      for (int j = 0; j < 4; j++) {
        int co = rowb + mi * 16 + j;
        sc[j] = gamma_p[co] * BN_RSQ; bt[j] = beta_p[co];
      }
#pragma unroll
      for (int ni = 0; ni < 4; ni++) {
        int col = colb + ni * 16;
        int b = col / 1600, hw = col - b * 1600;
#pragma unroll
        for (int j = 0; j < 4; j++) {
          int co = rowb + mi * 16 + j;
          out[((size_t)b * COUT + co) * HW + hw] = acc[mi][ni][j] * sc[j] + bt[j];
        }
      }
    }
  } else if (role == 1) {                    // conv1x1: et[b][hw][E] bf16
#pragma unroll
    for (int mi = 0; mi < 8; mi++) {
      float sc[4], bt[4];
#pragma unroll
      for (int j = 0; j < 4; j++) {
        int ech = rowb + mi * 16 + j;
        sc[j] = gamma_e[ech] * BN_RSQ; bt[j] = beta_e[ech];
      }
#pragma unroll
      for (int ni = 0; ni < 4; ni++) {
        int col = colb + ni * 16;
        int b = col / 1600, hw = col - b * 1600;
        ushort4 pk;
        pk.x = f2bf(acc[mi][ni][0] * sc[0] + bt[0]);
        pk.y = f2bf(acc[mi][ni][1] * sc[1] + bt[1]);
        pk.z = f2bf(acc[mi][ni][2] * sc[2] + bt[2]);
        pk.w = f2bf(acc[mi][ni][3] * sc[3] + bt[3]);
        *(ushort4*)(et + ((size_t)b * HW + hw) * E_ + (rowb + mi * 16)) = pk;
      }
    }
  } else {                                   // guide fc: gbf[token][e] bf16 (+bg)
#pragma unroll
    for (int mi = 0; mi < 8; mi++) {
      float bt[4];
#pragma unroll
      for (int j = 0; j < 4; j++) bt[j] = bg[rowb + mi * 16 + j];
#pragma unroll
      for (int ni = 0; ni < 4; ni++) {
        int col = colb + ni * 16;
        ushort4 pk;
        pk.x = f2bf(acc[mi][ni][0] + bt[0]);
        pk.y = f2bf(acc[mi][ni][1] + bt[1]);
        pk.z = f2bf(acc[mi][ni][2] + bt[2]);
        pk.w = f2bf(acc[mi][ni][3] + bt[3]);
        *(ushort4*)(gbf + (size_t)col * E_ + (rowb + mi * 16)) = pk;
      }
    }
  }
}

// ---- attn via MFMA: per (b,head): [HW x 32] . [32 x 80] -> max over 80, sigmoid ----
__global__ void k_attn_mfma(const unsigned short* __restrict__ et, const unsigned short* __restrict__ gbf,
                            const float* __restrict__ head_bias, float* __restrict__ attn) {
  __shared__ unsigned short gs[NTOK * HCH];   // [token][c] bf16, 5 KB
  int b = blockIdx.z, m = blockIdx.y;
  int tid = threadIdx.x, lane = tid & 63, wid = tid >> 6;
  for (int i = tid; i < NTOK * HCH / 8; i += 256) {
    int n = i >> 2, c = (i & 3) * 8;
    *(bf16x8*)&gs[n * HCH + c] = *(const bf16x8*)&gbf[((size_t)b * NTOK + n) * E_ + m * HCH + c];
  }
  __syncthreads();
  int col = lane & 15, kq = (lane >> 4) * 8;
  bf16x8 bfr[5];
#pragma unroll
  for (int ni = 0; ni < 5; ni++)
    bfr[ni] = *(const bf16x8*)&gs[(ni * 16 + col) * HCH + kq];

  int hw0 = blockIdx.x * 256 + wid * 64;
  bf16x8 afr[4];
#pragma unroll
  for (int mi = 0; mi < 4; mi++) {
    int hw = hw0 + mi * 16 + col; if (hw > HW - 1) hw = HW - 1;
    afr[mi] = *(const bf16x8*)&et[((size_t)b * HW + hw) * E_ + m * HCH + kq];
  }
  float hb = head_bias[m];
  float* attnp = attn + ((size_t)b * NHEAD + m) * HW;
#pragma unroll
  for (int mi = 0; mi < 4; mi++) {
    f32x4 d[5];
#pragma unroll
    for (int ni = 0; ni < 5; ni++) {
      f32x4 z = {0.f, 0.f, 0.f, 0.f};
      d[ni] = __builtin_amdgcn_mfma_f32_16x16x32_bf16(afr[mi], bfr[ni], z, 0, 0, 0);
    }
#pragma unroll
    for (int j = 0; j < 4; j++) {
      float v = fmaxf(fmaxf(fmaxf(d[0][j], d[1][j]), fmaxf(d[2][j], d[3][j])), d[4][j]);
      v = fmaxf(v, __shfl_xor(v, 1, 16));
      v = fmaxf(v, __shfl_xor(v, 2, 16));
      v = fmaxf(v, __shfl_xor(v, 4, 16));
      v = fmaxf(v, __shfl_xor(v, 8, 16));
      if (col == j) {
        int hwout = hw0 + mi * 16 + (lane >> 4) * 4 + j;
        if (hwout < HW)
          attnp[hwout] = 1.0f / (1.0f + __expf(-(v * 0.17677669529663687f + hb)));
      }
    }
  }
}

// ---- gate: out[b][co][hw] *= attn[b][co>>6][hw], in place, float4 ----
__global__ void k_gate(float* __restrict__ out, const float* __restrict__ attn) {
  int idx = blockIdx.x * 256 + threadIdx.x;       // 3276800 float4's
  int f4 = idx * 4;
  int b = f4 / (COUT * HW);
  int rem = f4 - b * (COUT * HW);
  int co = rem / HW, hw = rem - co * HW;
  float4 a = *(const float4*)(attn + ((size_t)b * NHEAD + (co >> 6)) * HW + hw);
  float4 p = ((float4*)out)[idx];
  p.x *= a.x; p.y *= a.y; p.z *= a.z; p.w *= a.w;
  ((float4*)out)[idx] = p;
}

extern "C" void kernel_launch(void* const* d_in, const int* in_sizes, int n_in,
                              void* d_out, int out_size, void* d_ws, size_t ws_size,
                              hipStream_t stream) {
  const float* x         = (const float*)d_in[0];
  const float* guide     = (const float*)d_in[1];
  const float* We        = (const float*)d_in[2];
  const float* gamma_e   = (const float*)d_in[3];
  const float* beta_e    = (const float*)d_in[4];
  const float* Wg        = (const float*)d_in[5];
  const float* bg        = (const float*)d_in[6];
  const float* head_bias = (const float*)d_in[7];
  const float* Wp        = (const float*)d_in[8];
  const float* gamma_p   = (const float*)d_in[9];
  const float* beta_p    = (const float*)d_in[10];
  float* out = (float*)d_out;

  char* ws = (char*)d_ws;
  size_t off = 0;
  auto alloc = [&](size_t bytes) { char* p = ws + off; off += (bytes + 255) & ~(size_t)255; return p; };
  unsigned short* xt   = (unsigned short*)alloc((size_t)B_ * SP * CIN * 2);
  unsigned short* wpb2 = (unsigned short*)alloc((size_t)COUT * 9 * CIN * 2);
  unsigned short* web  = (unsigned short*)alloc((size_t)E_ * CIN * 2);
  unsigned short* wgb  = (unsigned short*)alloc((size_t)E_ * CG * 2);
  unsigned short* gub  = (unsigned short*)alloc((size_t)B_ * NTOK * CG * 2);
  unsigned short* gbf  = (unsigned short*)alloc((size_t)B_ * NTOK * E_ * 2);
  unsigned short* et   = (unsigned short*)alloc((size_t)B_ * HW * E_ * 2);
  float* attn          = (float*)alloc((size_t)B_ * NHEAD * HW * 4);

  hipMemsetAsync(xt, 0, (size_t)B_ * SP * CIN * 2, stream);
  k_prep_x<<<dim3(50, 16, B_), dim3(32, 8), 0, stream>>>(x, xt);
  k_prep_wp<<<dim3(1024), dim3(256), 0, stream>>>(Wp, wpb2);
  k_cast_all<<<dim3(896), dim3(256), 0, stream>>>(We, web, Wg, wgb, guide, gub);
  k_fused<<<dim3(305), dim3(512), 0, stream>>>(wpb2, web, wgb, xt, gub,
      gamma_e, beta_e, gamma_p, beta_p, bg, out, et, gbf);
  k_attn_mfma<<<dim3(7, NHEAD, B_), dim3(256), 0, stream>>>(et, gbf, head_bias, attn);
  k_gate<<<dim3(12800), dim3(256), 0, stream>>>(out, attn);
}